// Round 2
// baseline (512.118 us; speedup 1.0000x reference)
//
#include <hip/hip_runtime.h>

typedef unsigned short ushort_t;
typedef __attribute__((ext_vector_type(8))) short short8;
typedef __attribute__((ext_vector_type(4))) float float4v;

#define E_N   4096
#define H_N   512
#define NH_N  4
#define HD_N  128
#define FFN_N 1024
#define H3_N  1536

__device__ __forceinline__ float bf2f(ushort_t u) {
  union { unsigned u; float f; } v; v.u = ((unsigned)u) << 16; return v.f;
}
__device__ __forceinline__ ushort_t f2bf(float f) {
  union { float f; unsigned u; } v; v.f = f;
  unsigned r = v.u + 0x7fffu + ((v.u >> 16) & 1u);
  return (ushort_t)(r >> 16);
}
// 8 consecutive fp32 -> 8 bf16 packed into uint4
__device__ __forceinline__ uint4 cvt8(const float* p) {
  float4 a = *(const float4*)p;
  float4 b = *(const float4*)(p + 4);
  union { ushort_t u[8]; uint4 v; } pk;
  pk.u[0] = f2bf(a.x); pk.u[1] = f2bf(a.y); pk.u[2] = f2bf(a.z); pk.u[3] = f2bf(a.w);
  pk.u[4] = f2bf(b.x); pk.u[5] = f2bf(b.y); pk.u[6] = f2bf(b.z); pk.u[7] = f2bf(b.w);
  return pk.v;
}

// ---------------------------------------------------------------------------
// bf16-MFMA GEMM: C[m][n] = epilogue( sum_k A[m][k] * W[n][k] + bias[n] )
// ASRC: 0 = workspace bf16, 1 = workspace fp32 (cvt8), 2 = d_in fp32 (cvt8).
// BN: 128 (grid.y = N/128) or 64 (grid.y = N/64, for N=512 load balance).
// 128xBN tile, BK=32, 4 waves (2x2), 16x16x32 MFMA. Layouts (m89/m91):
// A/B frag: idx=lane&15, k=quad*8+j ; C/D: col=lane&15, row=quad*4+reg.
// ---------------------------------------------------------------------------
enum { MODE_MSG = 0, MODE_GI = 1, MODE_GH = 2, MODE_QKV = 3, MODE_OUT = 4,
       MODE_LIN = 5, MODE_F1 = 6 };

template <int MODE, int ASRC, int BN>
__global__ __launch_bounds__(256, (BN == 64 ? 4 : 2)) void gemm_bt(
    const void* __restrict__ Av, const float* __restrict__ W,
    const float* __restrict__ bias, int K,
    float* __restrict__ outf, ushort_t* __restrict__ outb,
    const int* __restrict__ edge, float* __restrict__ aggf,
    const ushort_t* __restrict__ hres,
    ushort_t* __restrict__ qb, ushort_t* __restrict__ kb,
    ushort_t* __restrict__ vt)
{
  __shared__ ushort_t As[128 * 32];
  __shared__ ushort_t Bs[BN * 32];
  constexpr int NJ = BN / 32;   // N-fragments per wave

  const int tid  = threadIdx.x;
  const int lane = tid & 63;
  const int wave = tid >> 6;
  const int quad = lane >> 4;
  const int l15  = lane & 15;
  const int m0 = blockIdx.x * 128;
  const int n0 = blockIdx.y * BN;
  const int wm = (wave >> 1) * 64;
  const int wn = (wave & 1) * (BN / 2);

  float4v acc[4][NJ];
#pragma unroll
  for (int i = 0; i < 4; i++)
#pragma unroll
    for (int j = 0; j < NJ; j++)
#pragma unroll
      for (int r = 0; r < 4; r++) acc[i][j][r] = 0.f;

  const int sr = tid >> 2;
  const int sc = (tid & 3) * 8;

  for (int k0 = 0; k0 < K; k0 += 32) {
    __syncthreads();
    if constexpr (ASRC == 0) {
      const ushort_t* Ag = (const ushort_t*)Av + (size_t)(m0 + sr) * K + k0 + sc;
      *(uint4*)(&As[sr * 32 + sc])        = *(const uint4*)(Ag);
      *(uint4*)(&As[(sr + 64) * 32 + sc]) = *(const uint4*)(Ag + (size_t)64 * K);
    } else {
      const float* Ag = (const float*)Av + (size_t)(m0 + sr) * K + k0 + sc;
      *(uint4*)(&As[sr * 32 + sc])        = cvt8(Ag);
      *(uint4*)(&As[(sr + 64) * 32 + sc]) = cvt8(Ag + (size_t)64 * K);
    }
    {
      const float* Wg = W + (size_t)(n0 + sr) * K + k0 + sc;
      *(uint4*)(&Bs[sr * 32 + sc]) = cvt8(Wg);
      if constexpr (BN == 128)
        *(uint4*)(&Bs[(sr + 64) * 32 + sc]) = cvt8(Wg + (size_t)64 * K);
    }
    __syncthreads();

    short8 af[4], bfr[NJ];
#pragma unroll
    for (int i = 0; i < 4; i++)
      af[i] = *(const short8*)(&As[(wm + i * 16 + l15) * 32 + quad * 8]);
#pragma unroll
    for (int j = 0; j < NJ; j++)
      bfr[j] = *(const short8*)(&Bs[(wn + j * 16 + l15) * 32 + quad * 8]);
#pragma unroll
    for (int i = 0; i < 4; i++)
#pragma unroll
      for (int j = 0; j < NJ; j++)
        acc[i][j] = __builtin_amdgcn_mfma_f32_16x16x32_bf16(af[i], bfr[j],
                                                            acc[i][j], 0, 0, 0);
  }

#pragma unroll
  for (int j = 0; j < NJ; j++) {
    const int col = n0 + wn + j * 16 + l15;
    const float bv = bias[col];
#pragma unroll
    for (int i = 0; i < 4; i++) {
#pragma unroll
      for (int r = 0; r < 4; r++) {
        const int row = m0 + wm + i * 16 + quad * 4 + r;
        float v = acc[i][j][r] + bv;
        if constexpr (MODE == MODE_MSG) {
          v = fmaxf(v, 0.f);
          const int dst = edge[E_N + row] & (E_N - 1);  // edge_index[1][row]
          atomicAdd(&aggf[(size_t)dst * H_N + col], v);
        } else if constexpr (MODE == MODE_GI || MODE == MODE_GH) {
          outb[(size_t)row * H3_N + col] = f2bf(v);
        } else if constexpr (MODE == MODE_QKV) {
          const int part = col >> 9;         // 0=q 1=k 2=v
          const int hh   = (col >> 7) & 3;
          const int d    = col & 127;
          const ushort_t bvv = f2bf(v);
          if (part == 0)      qb[((size_t)hh * E_N + row) * HD_N + d] = bvv;
          else if (part == 1) kb[((size_t)hh * E_N + row) * HD_N + d] = bvv;
          else                vt[((size_t)hh * HD_N + d) * E_N + row] = bvv;  // V^T
        } else if constexpr (MODE == MODE_OUT) {
          v += bf2f(hres[(size_t)row * H_N + col]);   // residual y = o + h
          outf[(size_t)row * H_N + col] = v;
        } else if constexpr (MODE == MODE_LIN) {
          outb[(size_t)row * H_N + col] = f2bf(fmaxf(v, 0.f));
        } else {  // MODE_F1
          outb[(size_t)row * FFN_N + col] = f2bf(fmaxf(v, 0.f));
        }
      }
    }
  }
}

// ---------------------------------------------------------------------------
// Flash attention v3: grid 256 (1-D), 512 threads = 8 waves.
// head = bid & 3 so that (with id%8 XCD round-robin) each XCD serves exactly
// one head -> K+V (2 MB/head) stays L2-resident on its XCD.
// NO K/V LDS staging (K/V are L2-hot; staging + its 2 barriers/iter was the
// latency chain). K fragments read straight from global in the QK loop;
// V fragments prefetched into registers before softmax (latency hides under
// QK + softmax). Main loop has ZERO barriers -> 8 fully independent waves/CU.
// Waves 0-3: KV [0,2048), waves 4-7: KV [2048,4096); in-LDS flash merge.
// Ps (P-tile LDS round-trip) is wave-private: no barrier, 2-way bank alias.
// ---------------------------------------------------------------------------
__global__ __launch_bounds__(512, 2) void attn_kernel(
    const ushort_t* __restrict__ Qg, const ushort_t* __restrict__ Kg,
    const ushort_t* __restrict__ Vtg, ushort_t* __restrict__ Ob)
{
  const int bid  = blockIdx.x;
  const int head = bid & 3;
  const int qb0  = (bid >> 2) * 64;
  const int tid  = threadIdx.x;
  const int wave = tid >> 6;
  const int grp  = wave >> 2;     // 0/1: which KV half
  const int w4   = wave & 3;      // which 16-row Q sub-tile
  const int lane = tid & 63;
  const int quad = lane >> 4;
  const int l15  = lane & 15;

  __shared__ ushort_t Ps[8][16][72];   // per-wave P tile (18.4 KB)
  __shared__ float mO[64][128];        // merge buffer (32 KB)
  __shared__ float mML[64][2];

  const ushort_t* Qhead  = Qg  + (size_t)head * E_N * HD_N;
  const ushort_t* Khead  = Kg  + (size_t)head * E_N * HD_N;
  const ushort_t* Vthead = Vtg + (size_t)head * HD_N * E_N;

  // Q A-fragments: loop-invariant, in registers.
  short8 aq[4];
#pragma unroll
  for (int ks = 0; ks < 4; ks++)
    aq[ks] = *(const short8*)(Qhead +
        (size_t)(qb0 + w4 * 16 + l15) * HD_N + ks * 32 + quad * 8);

  float4v oacc[8];
#pragma unroll
  for (int i = 0; i < 8; i++)
#pragma unroll
    for (int r = 0; r < 4; r++) oacc[i][r] = 0.f;
  float mprev[4], lsum[4];
#pragma unroll
  for (int r = 0; r < 4; r++) { mprev[r] = -1e30f; lsum[r] = 0.f; }

  const float scale = 0.088388347648318447f;  // 1/sqrt(128)

  const int kt0 = grp * 2048;
  for (int kt = kt0; kt < kt0 + 2048; kt += 64) {
    // Prefetch V fragments (independent of K/QK; latency hides under QK+softmax).
    short8 vf[2][8];
#pragma unroll
    for (int ks2 = 0; ks2 < 2; ks2++)
#pragma unroll
      for (int j = 0; j < 8; j++)
        vf[ks2][j] = *(const short8*)(Vthead +
            (size_t)(j * 16 + l15) * E_N + kt + ks2 * 32 + quad * 8);

    // QK^T: K B-fragments straight from global (L2-hot; 16 rows x 64B/instr).
    float4v sacc[4];
#pragma unroll
    for (int j = 0; j < 4; j++)
#pragma unroll
      for (int r = 0; r < 4; r++) sacc[j][r] = 0.f;
    __builtin_amdgcn_s_setprio(1);
#pragma unroll
    for (int ks = 0; ks < 4; ks++) {
#pragma unroll
      for (int j = 0; j < 4; j++) {
        short8 bk = *(const short8*)(Khead +
            (size_t)(kt + j * 16 + l15) * HD_N + ks * 32 + quad * 8);
        sacc[j] = __builtin_amdgcn_mfma_f32_16x16x32_bf16(aq[ks], bk, sacc[j], 0, 0, 0);
      }
    }
    __builtin_amdgcn_s_setprio(0);

    float alpha[4], pv[4][4];
#pragma unroll
    for (int r = 0; r < 4; r++) {
      float mx = -1e30f;
#pragma unroll
      for (int j = 0; j < 4; j++) { float s = sacc[j][r] * scale; pv[j][r] = s; mx = fmaxf(mx, s); }
#pragma unroll
      for (int off = 1; off < 16; off <<= 1) mx = fmaxf(mx, __shfl_xor(mx, off, 64));
      float mnew = fmaxf(mprev[r], mx);
      alpha[r] = __expf(mprev[r] - mnew);
      float ss = 0.f;
#pragma unroll
      for (int j = 0; j < 4; j++) { float p = __expf(pv[j][r] - mnew); pv[j][r] = p; ss += p; }
#pragma unroll
      for (int off = 1; off < 16; off <<= 1) ss += __shfl_xor(ss, off, 64);
      lsum[r] = lsum[r] * alpha[r] + ss;
      mprev[r] = mnew;
    }
#pragma unroll
    for (int i = 0; i < 8; i++)
#pragma unroll
      for (int r = 0; r < 4; r++) oacc[i][r] *= alpha[r];

    // P tile is wave-private: within-wave lgkmcnt ordering suffices, no barrier.
#pragma unroll
    for (int j = 0; j < 4; j++)
#pragma unroll
      for (int r = 0; r < 4; r++)
        Ps[wave][quad * 4 + r][j * 16 + l15] = f2bf(pv[j][r]);

    __builtin_amdgcn_s_setprio(1);
#pragma unroll
    for (int ks2 = 0; ks2 < 2; ks2++) {
      short8 ap = *(const short8*)(&Ps[wave][l15][ks2 * 32 + quad * 8]);
#pragma unroll
      for (int j = 0; j < 8; j++)
        oacc[j] = __builtin_amdgcn_mfma_f32_16x16x32_bf16(ap, vf[ks2][j], oacc[j], 0, 0, 0);
    }
    __builtin_amdgcn_s_setprio(0);
  }

  // ---- merge the two KV halves (flash combine), group1 -> LDS -> group0 ----
  __syncthreads();
  if (grp == 1) {
#pragma unroll
    for (int j = 0; j < 8; j++)
#pragma unroll
      for (int r = 0; r < 4; r++)
        mO[w4 * 16 + quad * 4 + r][j * 16 + l15] = oacc[j][r];
    if (l15 == 0) {
#pragma unroll
      for (int r = 0; r < 4; r++) {
        mML[w4 * 16 + quad * 4 + r][0] = mprev[r];
        mML[w4 * 16 + quad * 4 + r][1] = lsum[r];
      }
    }
  }
  __syncthreads();
  if (grp == 0) {
    float s0[4], s1[4];
#pragma unroll
    for (int r = 0; r < 4; r++) {
      int rr = w4 * 16 + quad * 4 + r;
      float m1 = mML[rr][0], l1 = mML[rr][1];
      float m  = fmaxf(mprev[r], m1);
      float e0 = __expf(mprev[r] - m);
      float e1 = __expf(m1 - m);
      float inv = 1.f / (lsum[r] * e0 + l1 * e1);
      s0[r] = e0 * inv;
      s1[r] = e1 * inv;
    }
#pragma unroll
    for (int j = 0; j < 8; j++)
#pragma unroll
      for (int r = 0; r < 4; r++) {
        int row = qb0 + w4 * 16 + quad * 4 + r;
        int col = head * HD_N + j * 16 + l15;
        float o1 = mO[w4 * 16 + quad * 4 + r][j * 16 + l15];
        Ob[(size_t)row * H_N + col] = f2bf(oacc[j][r] * s0[r] + o1 * s1[r]);
      }
  }
}

// ---------------------------------------------------------------------------
__global__ __launch_bounds__(256) void zero_f32_kernel(float4* p) {
  p[blockIdx.x * 256 + threadIdx.x] = make_float4(0.f, 0.f, 0.f, 0.f);
}

__global__ __launch_bounds__(256) void gru_kernel(
    const ushort_t* __restrict__ gib, const ushort_t* __restrict__ ghb,
    const float* __restrict__ x, ushort_t* __restrict__ hb) {
  int idx = blockIdx.x * 256 + threadIdx.x;       // E*H
  int e = idx >> 9, j = idx & 511;
  size_t b = (size_t)e * H3_N;
  float ir = bf2f(gib[b + j]), iz = bf2f(gib[b + 512 + j]), inn = bf2f(gib[b + 1024 + j]);
  float hr = bf2f(ghb[b + j]), hz = bf2f(ghb[b + 512 + j]), hn  = bf2f(ghb[b + 1024 + j]);
  float r = 1.f / (1.f + __expf(-(ir + hr)));
  float z = 1.f / (1.f + __expf(-(iz + hz)));
  float n = tanhf(inn + r * hn);
  float h = (1.f - z) * n + z * x[idx];
  hb[idx] = f2bf(h);
}

__global__ __launch_bounds__(256) void ln_kernel(
    const float* __restrict__ y, const float* __restrict__ g,
    const float* __restrict__ b, ushort_t* __restrict__ yn) {
  int wave = threadIdx.x >> 6, lane = threadIdx.x & 63;
  int row = blockIdx.x * 4 + wave;
  const float* yr = y + (size_t)row * H_N;
  float v[8], s = 0.f;
#pragma unroll
  for (int i = 0; i < 8; i++) { v[i] = yr[lane + i * 64]; s += v[i]; }
#pragma unroll
  for (int off = 1; off < 64; off <<= 1) s += __shfl_xor(s, off, 64);
  float mu = s * (1.f / 512.f);
  float q = 0.f;
#pragma unroll
  for (int i = 0; i < 8; i++) { float d = v[i] - mu; q += d * d; }
#pragma unroll
  for (int off = 1; off < 64; off <<= 1) q += __shfl_xor(q, off, 64);
  float rstd = rsqrtf(q * (1.f / 512.f) + 1e-5f);
#pragma unroll
  for (int i = 0; i < 8; i++) {
    int c = lane + i * 64;
    yn[(size_t)row * H_N + c] = f2bf((v[i] - mu) * rstd * g[c] + b[c]);
  }
}

// final: out[row] = f[row,:] . W_f2 + b_f2  -- FP32 STORE (d_out is float*)
__global__ __launch_bounds__(256) void f2_kernel(
    const ushort_t* __restrict__ fb, const float* __restrict__ w,
    const float* __restrict__ b2, float* __restrict__ out) {
  int wave = threadIdx.x >> 6, lane = threadIdx.x & 63;
  int row = blockIdx.x * 4 + wave;
  const ushort_t* fr = fb + (size_t)row * FFN_N;
  float s = 0.f;
#pragma unroll
  for (int i = 0; i < 16; i++) { int c = lane + i * 64; s += bf2f(fr[c]) * w[c]; }
#pragma unroll
  for (int off = 1; off < 64; off <<= 1) s += __shfl_xor(s, off, 64);
  if (lane == 0) out[row] = s + b2[0];
}

// ---------------------------------------------------------------------------
extern "C" void kernel_launch(void* const* d_in, const int* in_sizes, int n_in,
                              void* d_out, int out_size, void* d_ws, size_t ws_size,
                              hipStream_t stream) {
  const float* x     = (const float*)d_in[0];
  const int*   edge  = (const int*)d_in[1];
  const float* W_msg = (const float*)d_in[2];
  const float* b_msg = (const float*)d_in[3];
  const float* W_ih  = (const float*)d_in[4];
  const float* b_ih  = (const float*)d_in[5];
  const float* W_hh  = (const float*)d_in[6];
  const float* b_hh  = (const float*)d_in[7];
  const float* W_in  = (const float*)d_in[8];
  const float* b_in  = (const float*)d_in[9];
  const float* W_out = (const float*)d_in[10];
  const float* b_out = (const float*)d_in[11];
  const float* ln_g  = (const float*)d_in[12];
  const float* ln_b  = (const float*)d_in[13];
  const float* W_lin = (const float*)d_in[14];
  const float* b_lin = (const float*)d_in[15];
  const float* W_f1  = (const float*)d_in[16];
  const float* b_f1  = (const float*)d_in[17];
  const float* W_f2  = (const float*)d_in[18];
  const float* b_f2  = (const float*)d_in[19];

  char* ws = (char*)d_ws;
  const size_t MB = 1024 * 1024;
  // Workspace: peak 33 MB, liveness-packed.
  float*    agg = (float*)(ws + 1 * MB);           // [1,9)   zero..GI
  ushort_t* hb  = (ushort_t*)(ws + 1 * MB);        // [1,5)   gru..OUT (agg dead)
  ushort_t* gib = (ushort_t*)(ws + 9 * MB);        // [9,21)  bf16 [E][3H], GI..gru
  ushort_t* ghb = (ushort_t*)(ws + 21 * MB);       // [21,33) bf16 [E][3H], GH..gru
  ushort_t* Qb  = (ushort_t*)(ws + 5 * MB);        // [5,9)   QKV..attn
  ushort_t* Kb  = (ushort_t*)(ws + 9 * MB);        // [9,13)  (gib dead)
  ushort_t* Vt  = (ushort_t*)(ws + 13 * MB);       // [13,17)
  ushort_t* ob  = (ushort_t*)(ws + 17 * MB);       // [17,21) attn..OUT
  float*    y   = (float*)(ws + 21 * MB);          // [21,29) fp32, OUT..ln (ghb dead)
  ushort_t* ynb = (ushort_t*)(ws + 29 * MB);       // [29,31) ln..LIN
  ushort_t* gb  = (ushort_t*)(ws + 31 * MB);       // [31,33) LIN..F1
  ushort_t* fb  = (ushort_t*)(ws + 5 * MB);        // [5,13)  bf16 [E][FFN], F1..f2

  zero_f32_kernel<<<2048, 256, 0, stream>>>((float4*)agg);

  gemm_bt<MODE_MSG, 2, 64><<<dim3(32, 8), 256, 0, stream>>>(
      x, W_msg, b_msg, H_N, nullptr, nullptr, edge, agg, nullptr,
      nullptr, nullptr, nullptr);

  gemm_bt<MODE_GI, 1, 128><<<dim3(32, 12), 256, 0, stream>>>(
      agg, W_ih, b_ih, H_N, nullptr, gib, nullptr, nullptr, nullptr,
      nullptr, nullptr, nullptr);

  gemm_bt<MODE_GH, 2, 128><<<dim3(32, 12), 256, 0, stream>>>(
      x, W_hh, b_hh, H_N, nullptr, ghb, nullptr, nullptr, nullptr,
      nullptr, nullptr, nullptr);

  gru_kernel<<<8192, 256, 0, stream>>>(gib, ghb, x, hb);

  gemm_bt<MODE_QKV, 0, 128><<<dim3(32, 12), 256, 0, stream>>>(
      hb, W_in, b_in, H_N, nullptr, nullptr, nullptr, nullptr, nullptr,
      Qb, Kb, Vt);

  attn_kernel<<<256, 512, 0, stream>>>(Qb, Kb, Vt, ob);

  gemm_bt<MODE_OUT, 0, 64><<<dim3(32, 8), 256, 0, stream>>>(
      ob, W_out, b_out, H_N, y, nullptr, nullptr, nullptr, hb,
      nullptr, nullptr, nullptr);

  ln_kernel<<<1024, 256, 0, stream>>>(y, ln_g, ln_b, ynb);

  gemm_bt<MODE_LIN, 0, 64><<<dim3(32, 8), 256, 0, stream>>>(
      ynb, W_lin, b_lin, H_N, nullptr, gb, nullptr, nullptr, nullptr,
      nullptr, nullptr, nullptr);

  gemm_bt<MODE_F1, 0, 128><<<dim3(32, 8), 256, 0, stream>>>(
      gb, W_f1, b_f1, H_N, nullptr, fb, nullptr, nullptr, nullptr,
      nullptr, nullptr, nullptr);

  f2_kernel<<<1024, 256, 0, stream>>>(fb, W_f2, b_f2, (float*)d_out);
}

// Round 3
// 398.502 us; speedup vs baseline: 1.2851x; 1.2851x over previous
//
#include <hip/hip_runtime.h>

typedef unsigned short ushort_t;
typedef __attribute__((ext_vector_type(8))) short short8;
typedef __attribute__((ext_vector_type(4))) float float4v;

#define E_N   4096
#define H_N   512
#define NH_N  4
#define HD_N  128
#define FFN_N 1024
#define H3_N  1536

__device__ __forceinline__ float bf2f(ushort_t u) {
  union { unsigned u; float f; } v; v.u = ((unsigned)u) << 16; return v.f;
}
__device__ __forceinline__ ushort_t f2bf(float f) {
  union { float f; unsigned u; } v; v.f = f;
  unsigned r = v.u + 0x7fffu + ((v.u >> 16) & 1u);
  return (ushort_t)(r >> 16);
}
// 8 consecutive fp32 -> 8 bf16 packed into uint4
__device__ __forceinline__ uint4 cvt8(const float* p) {
  float4 a = *(const float4*)p;
  float4 b = *(const float4*)(p + 4);
  union { ushort_t u[8]; uint4 v; } pk;
  pk.u[0] = f2bf(a.x); pk.u[1] = f2bf(a.y); pk.u[2] = f2bf(a.z); pk.u[3] = f2bf(a.w);
  pk.u[4] = f2bf(b.x); pk.u[5] = f2bf(b.y); pk.u[6] = f2bf(b.z); pk.u[7] = f2bf(b.w);
  return pk.v;
}
__device__ __forceinline__ uint4 cvt8v(float4 a, float4 b) {
  union { ushort_t u[8]; uint4 v; } pk;
  pk.u[0] = f2bf(a.x); pk.u[1] = f2bf(a.y); pk.u[2] = f2bf(a.z); pk.u[3] = f2bf(a.w);
  pk.u[4] = f2bf(b.x); pk.u[5] = f2bf(b.y); pk.u[6] = f2bf(b.z); pk.u[7] = f2bf(b.w);
  return pk.v;
}

// ---------------------------------------------------------------------------
// One-shot fp32->bf16 conversion of x + all weight matrices into a contiguous
// bf16 workspace region. Segment boundaries (elems, all %8==0):
//   x:[0,2097152) Wmsg:[..2359296) Wih:[..3145728) Whh:[..3932160)
//   Win:[..4718592) Wout:[..4980736) Wlin:[..5242880) Wf1:[..5767168)
// ---------------------------------------------------------------------------
__global__ __launch_bounds__(256) void cvt_ws_kernel(
    const float* __restrict__ x, const float* __restrict__ wmsg,
    const float* __restrict__ wih, const float* __restrict__ whh,
    const float* __restrict__ win, const float* __restrict__ wout,
    const float* __restrict__ wlin, const float* __restrict__ wf1,
    ushort_t* __restrict__ dst)
{
  size_t o = ((size_t)blockIdx.x * 256 + threadIdx.x) * 8;
  const float* s;
  if      (o < 2097152) s = x    + o;
  else if (o < 2359296) s = wmsg + (o - 2097152);
  else if (o < 3145728) s = wih  + (o - 2359296);
  else if (o < 3932160) s = whh  + (o - 3145728);
  else if (o < 4718592) s = win  + (o - 3932160);
  else if (o < 4980736) s = wout + (o - 4718592);
  else if (o < 5242880) s = wlin + (o - 4980736);
  else                  s = wf1  + (o - 5242880);
  *(uint4*)(dst + o) = cvt8(s);
}

// ---------------------------------------------------------------------------
// bf16-MFMA GEMM: C[m][n] = epilogue( sum_k A[m][k] * W[n][k] + bias[n] )
// W is PRE-CONVERTED bf16 (torch layout [N,K]).
// ASRC: 0 = bf16 A, 1 = fp32 A (cvt8 at LDS-write time).
// 128x64 tile, BK=64, 4 waves (2x2), 16x16x32 MFMA, T14 reg-prefetch:
//   { sync; ds_write staged regs; sync; issue next-tile loads; compute }
// so global latency overlaps MFMA instead of sitting between barriers.
// LDS rows XOR-swizzled (byte ^= (row&7)<<4): stride-128B rows would
// otherwise be a 32-way bank conflict on ds_read_b128 (G4).
// 24 KB LDS + ~120 VGPR -> 3-4 blocks/CU co-resident.
// ---------------------------------------------------------------------------
enum { MODE_MSG = 0, MODE_GI = 1, MODE_GH = 2, MODE_QKV = 3, MODE_OUT = 4,
       MODE_LIN = 5, MODE_F1 = 6 };

template <int MODE, int ASRC>
__global__ __launch_bounds__(256, 2) void gemm_bt(
    const void* __restrict__ Av, const ushort_t* __restrict__ W,
    const float* __restrict__ bias, int K,
    float* __restrict__ outf, ushort_t* __restrict__ outb,
    const int* __restrict__ edge, float* __restrict__ aggf,
    const ushort_t* __restrict__ hres,
    ushort_t* __restrict__ qb, ushort_t* __restrict__ kb,
    ushort_t* __restrict__ vt)
{
  __shared__ ushort_t As[128 * 64];
  __shared__ ushort_t Bs[64 * 64];

  const int tid  = threadIdx.x;
  const int lane = tid & 63;
  const int wave = tid >> 6;
  const int quad = lane >> 4;
  const int l15  = lane & 15;
  const int m0 = blockIdx.x * 128;
  const int n0 = blockIdx.y * 64;
  const int wm = (wave >> 1) * 64;
  const int wn = (wave & 1) * 32;

  float4v acc[4][2];
#pragma unroll
  for (int i = 0; i < 4; i++)
#pragma unroll
    for (int j = 0; j < 2; j++)
#pragma unroll
      for (int r = 0; r < 4; r++) acc[i][j][r] = 0.f;

  // staging coords: thread covers rows {ar+32i}, 8 cols at ac.
  const int ar = tid >> 3;
  const int ac = (tid & 7) * 8;
  const int awb = (ac * 2) ^ ((ar & 7) << 4);   // swizzled byte col
  const int rmask = (l15 & 7) << 4;             // read-side swizzle mask

  uint4  pa[4], pb[2];
  float4 fa[8];

#define LOADA(KK)                                                              \
  do {                                                                         \
    if constexpr (ASRC == 0) {                                                 \
      const ushort_t* Ab = (const ushort_t*)Av;                                \
      _Pragma("unroll")                                                        \
      for (int i = 0; i < 4; i++)                                              \
        pa[i] = *(const uint4*)(Ab + (size_t)(m0 + ar + 32 * i) * K + (KK) + ac); \
    } else {                                                                   \
      const float* Af = (const float*)Av;                                      \
      _Pragma("unroll")                                                        \
      for (int i = 0; i < 4; i++) {                                            \
        const float* p = Af + (size_t)(m0 + ar + 32 * i) * K + (KK) + ac;      \
        fa[2 * i]     = *(const float4*)(p);                                   \
        fa[2 * i + 1] = *(const float4*)(p + 4);                               \
      }                                                                        \
    }                                                                          \
  } while (0)

#define LOADB(KK)                                                              \
  do {                                                                         \
    _Pragma("unroll")                                                          \
    for (int i = 0; i < 2; i++)                                                \
      pb[i] = *(const uint4*)(W + (size_t)(n0 + ar + 32 * i) * K + (KK) + ac); \
  } while (0)

  LOADA(0);
  LOADB(0);

  for (int k0 = 0; k0 < K; k0 += 64) {
    __syncthreads();
#pragma unroll
    for (int i = 0; i < 4; i++) {
      uint4 v;
      if constexpr (ASRC == 0) v = pa[i];
      else                     v = cvt8v(fa[2 * i], fa[2 * i + 1]);
      *(uint4*)((char*)As + (ar + 32 * i) * 128 + awb) = v;
    }
#pragma unroll
    for (int i = 0; i < 2; i++)
      *(uint4*)((char*)Bs + (ar + 32 * i) * 128 + awb) = pb[i];
    __syncthreads();

    if (k0 + 64 < K) { LOADA(k0 + 64); LOADB(k0 + 64); }

#pragma unroll
    for (int ks = 0; ks < 2; ks++) {
      short8 af[4], bfr[2];
#pragma unroll
      for (int i = 0; i < 4; i++)
        af[i] = *(const short8*)((const char*)As +
                 (wm + i * 16 + l15) * 128 + ((ks * 64 + quad * 16) ^ rmask));
#pragma unroll
      for (int j = 0; j < 2; j++)
        bfr[j] = *(const short8*)((const char*)Bs +
                 (wn + j * 16 + l15) * 128 + ((ks * 64 + quad * 16) ^ rmask));
#pragma unroll
      for (int i = 0; i < 4; i++)
#pragma unroll
        for (int j = 0; j < 2; j++)
          acc[i][j] = __builtin_amdgcn_mfma_f32_16x16x32_bf16(af[i], bfr[j],
                                                              acc[i][j], 0, 0, 0);
    }
  }
#undef LOADA
#undef LOADB

#pragma unroll
  for (int j = 0; j < 2; j++) {
    const int col = n0 + wn + j * 16 + l15;
    const float bv = bias[col];
#pragma unroll
    for (int i = 0; i < 4; i++) {
#pragma unroll
      for (int r = 0; r < 4; r++) {
        const int row = m0 + wm + i * 16 + quad * 4 + r;
        float v = acc[i][j][r] + bv;
        if constexpr (MODE == MODE_MSG) {
          v = fmaxf(v, 0.f);
          const int dst = edge[E_N + row] & (E_N - 1);  // edge_index[1][row]
          atomicAdd(&aggf[(size_t)dst * H_N + col], v);
        } else if constexpr (MODE == MODE_GI || MODE == MODE_GH) {
          outb[(size_t)row * H3_N + col] = f2bf(v);
        } else if constexpr (MODE == MODE_QKV) {
          const int part = col >> 9;         // 0=q 1=k 2=v
          const int hh   = (col >> 7) & 3;
          const int d    = col & 127;
          const ushort_t bvv = f2bf(v);
          if (part == 0)      qb[((size_t)hh * E_N + row) * HD_N + d] = bvv;
          else if (part == 1) kb[((size_t)hh * E_N + row) * HD_N + d] = bvv;
          else                vt[((size_t)hh * HD_N + d) * E_N + row] = bvv;  // V^T
        } else if constexpr (MODE == MODE_OUT) {
          v += bf2f(hres[(size_t)row * H_N + col]);   // residual y = o + h
          outf[(size_t)row * H_N + col] = v;
        } else if constexpr (MODE == MODE_LIN) {
          outb[(size_t)row * H_N + col] = f2bf(fmaxf(v, 0.f));
        } else {  // MODE_F1
          outb[(size_t)row * FFN_N + col] = f2bf(fmaxf(v, 0.f));
        }
      }
    }
  }
}

// ---------------------------------------------------------------------------
// Flash attention (r1 structure + T14 reg-prefetch): grid (E/64, NH),
// 512 threads = 8 waves. Waves 0-3: KV [0,2048), waves 4-7: KV [2048,4096)
// for the same 64-row Q tile; private LDS K/V/P per group; in-LDS merge.
// Next K/V tile is loaded into REGISTERS during compute, so the
// inter-barrier section is only the fast ds_write (global latency hidden).
// ---------------------------------------------------------------------------
__global__ __launch_bounds__(512, 2) void attn_kernel(
    const ushort_t* __restrict__ Qg, const ushort_t* __restrict__ Kg,
    const ushort_t* __restrict__ Vtg, ushort_t* __restrict__ Ob)
{
  const int qb0  = blockIdx.x * 64;
  const int head = blockIdx.y;
  const int tid  = threadIdx.x;
  const int wave = tid >> 6;
  const int grp  = wave >> 2;     // 0/1: which KV half
  const int w4   = wave & 3;      // which 16-row Q sub-tile
  const int gtid = tid & 255;     // thread id within group (staging)
  const int lane = tid & 63;
  const int quad = lane >> 4;
  const int l15  = lane & 15;

  __shared__ ushort_t Ks[2][64][136];
  __shared__ ushort_t Vs[2][128][72];
  __shared__ ushort_t Ps[2][4][16][72];

  const ushort_t* Qhead  = Qg  + (size_t)head * E_N * HD_N;
  const ushort_t* Khead  = Kg  + (size_t)head * E_N * HD_N;
  const ushort_t* Vthead = Vtg + (size_t)head * HD_N * E_N;

  // Q A-fragments: loop-invariant, in registers.
  short8 aq[4];
#pragma unroll
  for (int ks = 0; ks < 4; ks++)
    aq[ks] = *(const short8*)(Qhead +
        (size_t)(qb0 + w4 * 16 + l15) * HD_N + ks * 32 + quad * 8);

  float4v oacc[8];
#pragma unroll
  for (int i = 0; i < 8; i++)
#pragma unroll
    for (int r = 0; r < 4; r++) oacc[i][r] = 0.f;
  float mprev[4], lsum[4];
#pragma unroll
  for (int r = 0; r < 4; r++) { mprev[r] = -1e30f; lsum[r] = 0.f; }

  const float scale = 0.088388347648318447f;  // 1/sqrt(128)

  // staging coords (derived from r1's c = gtid + 256*i loops)
  const int gr  = gtid >> 4, gc8 = (gtid & 15) * 8;   // K: rows gr+16i
  const int vrr = gtid >> 3, vc8 = (gtid & 7) * 8;    // V: rows vrr+32i

  const int kt0 = grp * 2048;
  uint4 kr[4], vr[4];
#pragma unroll
  for (int i = 0; i < 4; i++) {
    kr[i] = *(const uint4*)(Khead + (size_t)(kt0 + gr + 16 * i) * HD_N + gc8);
    vr[i] = *(const uint4*)(Vthead + (size_t)(vrr + 32 * i) * E_N + kt0 + vc8);
  }

  for (int kt = kt0; kt < kt0 + 2048; kt += 64) {
    __syncthreads();
#pragma unroll
    for (int i = 0; i < 4; i++) {
      *(uint4*)(&Ks[grp][gr + 16 * i][gc8])  = kr[i];
      *(uint4*)(&Vs[grp][vrr + 32 * i][vc8]) = vr[i];
    }
    __syncthreads();

    if (kt + 64 < kt0 + 2048) {
#pragma unroll
      for (int i = 0; i < 4; i++) {
        kr[i] = *(const uint4*)(Khead + (size_t)(kt + 64 + gr + 16 * i) * HD_N + gc8);
        vr[i] = *(const uint4*)(Vthead + (size_t)(vrr + 32 * i) * E_N + kt + 64 + vc8);
      }
    }

    float4v sacc[4];
#pragma unroll
    for (int j = 0; j < 4; j++)
#pragma unroll
      for (int r = 0; r < 4; r++) sacc[j][r] = 0.f;
#pragma unroll
    for (int ks = 0; ks < 4; ks++) {
#pragma unroll
      for (int j = 0; j < 4; j++) {
        short8 bk = *(const short8*)(&Ks[grp][j * 16 + l15][ks * 32 + quad * 8]);
        sacc[j] = __builtin_amdgcn_mfma_f32_16x16x32_bf16(aq[ks], bk, sacc[j], 0, 0, 0);
      }
    }

    float alpha[4], pv[4][4];
#pragma unroll
    for (int r = 0; r < 4; r++) {
      float mx = -1e30f;
#pragma unroll
      for (int j = 0; j < 4; j++) { float s = sacc[j][r] * scale; pv[j][r] = s; mx = fmaxf(mx, s); }
#pragma unroll
      for (int off = 1; off < 16; off <<= 1) mx = fmaxf(mx, __shfl_xor(mx, off, 64));
      float mnew = fmaxf(mprev[r], mx);
      alpha[r] = __expf(mprev[r] - mnew);
      float ss = 0.f;
#pragma unroll
      for (int j = 0; j < 4; j++) { float p = __expf(pv[j][r] - mnew); pv[j][r] = p; ss += p; }
#pragma unroll
      for (int off = 1; off < 16; off <<= 1) ss += __shfl_xor(ss, off, 64);
      lsum[r] = lsum[r] * alpha[r] + ss;
      mprev[r] = mnew;
    }
#pragma unroll
    for (int i = 0; i < 8; i++)
#pragma unroll
      for (int r = 0; r < 4; r++) oacc[i][r] *= alpha[r];

    // P tile is wave-private: within-wave lgkmcnt ordering suffices, no barrier.
#pragma unroll
    for (int j = 0; j < 4; j++)
#pragma unroll
      for (int r = 0; r < 4; r++)
        Ps[grp][w4][quad * 4 + r][j * 16 + l15] = f2bf(pv[j][r]);

#pragma unroll
    for (int ks2 = 0; ks2 < 2; ks2++) {
      short8 ap = *(const short8*)(&Ps[grp][w4][l15][ks2 * 32 + quad * 8]);
#pragma unroll
      for (int j = 0; j < 8; j++) {
        short8 bv = *(const short8*)(&Vs[grp][j * 16 + l15][ks2 * 32 + quad * 8]);
        oacc[j] = __builtin_amdgcn_mfma_f32_16x16x32_bf16(ap, bv, oacc[j], 0, 0, 0);
      }
    }
  }

  // ---- merge the two KV halves (flash combine), group1 -> LDS -> group0 ----
  __syncthreads();
  float* mO  = (float*)Ks;   // [64][128] fp32 = 32 KB  (Ks is 34816 B)
  float* mML = (float*)Vs;   // [64][2]   fp32          (Vs is 36864 B)
  if (grp == 1) {
#pragma unroll
    for (int j = 0; j < 8; j++)
#pragma unroll
      for (int r = 0; r < 4; r++)
        mO[(w4 * 16 + quad * 4 + r) * 128 + j * 16 + l15] = oacc[j][r];
    if (l15 == 0) {
#pragma unroll
      for (int r = 0; r < 4; r++) {
        mML[(w4 * 16 + quad * 4 + r) * 2 + 0] = mprev[r];
        mML[(w4 * 16 + quad * 4 + r) * 2 + 1] = lsum[r];
      }
    }
  }
  __syncthreads();
  if (grp == 0) {
    float s0[4], s1[4];
#pragma unroll
    for (int r = 0; r < 4; r++) {
      int rr = w4 * 16 + quad * 4 + r;
      float m1 = mML[rr * 2 + 0], l1 = mML[rr * 2 + 1];
      float m  = fmaxf(mprev[r], m1);
      float e0 = __expf(mprev[r] - m);
      float e1 = __expf(m1 - m);
      float inv = 1.f / (lsum[r] * e0 + l1 * e1);
      s0[r] = e0 * inv;
      s1[r] = e1 * inv;
    }
#pragma unroll
    for (int j = 0; j < 8; j++)
#pragma unroll
      for (int r = 0; r < 4; r++) {
        int row = qb0 + w4 * 16 + quad * 4 + r;
        int col = head * HD_N + j * 16 + l15;
        float o1 = mO[(w4 * 16 + quad * 4 + r) * 128 + j * 16 + l15];
        Ob[(size_t)row * H_N + col] = f2bf(oacc[j][r] * s0[r] + o1 * s1[r]);
      }
  }
}

// ---------------------------------------------------------------------------
__global__ __launch_bounds__(256) void zero_f32_kernel(float4* p) {
  p[blockIdx.x * 256 + threadIdx.x] = make_float4(0.f, 0.f, 0.f, 0.f);
}

__global__ __launch_bounds__(256) void gru_kernel(
    const ushort_t* __restrict__ gib, const ushort_t* __restrict__ ghb,
    const float* __restrict__ x, ushort_t* __restrict__ hb) {
  int idx = blockIdx.x * 256 + threadIdx.x;       // E*H
  int e = idx >> 9, j = idx & 511;
  size_t b = (size_t)e * H3_N;
  float ir = bf2f(gib[b + j]), iz = bf2f(gib[b + 512 + j]), inn = bf2f(gib[b + 1024 + j]);
  float hr = bf2f(ghb[b + j]), hz = bf2f(ghb[b + 512 + j]), hn  = bf2f(ghb[b + 1024 + j]);
  float r = 1.f / (1.f + __expf(-(ir + hr)));
  float z = 1.f / (1.f + __expf(-(iz + hz)));
  float n = tanhf(inn + r * hn);
  float h = (1.f - z) * n + z * x[idx];
  hb[idx] = f2bf(h);
}

__global__ __launch_bounds__(256) void ln_kernel(
    const float* __restrict__ y, const float* __restrict__ g,
    const float* __restrict__ b, ushort_t* __restrict__ yn) {
  int wave = threadIdx.x >> 6, lane = threadIdx.x & 63;
  int row = blockIdx.x * 4 + wave;
  const float* yr = y + (size_t)row * H_N;
  float v[8], s = 0.f;
#pragma unroll
  for (int i = 0; i < 8; i++) { v[i] = yr[lane + i * 64]; s += v[i]; }
#pragma unroll
  for (int off = 1; off < 64; off <<= 1) s += __shfl_xor(s, off, 64);
  float mu = s * (1.f / 512.f);
  float q = 0.f;
#pragma unroll
  for (int i = 0; i < 8; i++) { float d = v[i] - mu; q += d * d; }
#pragma unroll
  for (int off = 1; off < 64; off <<= 1) q += __shfl_xor(q, off, 64);
  float rstd = rsqrtf(q * (1.f / 512.f) + 1e-5f);
#pragma unroll
  for (int i = 0; i < 8; i++) {
    int c = lane + i * 64;
    yn[(size_t)row * H_N + c] = f2bf((v[i] - mu) * rstd * g[c] + b[c]);
  }
}

// final: out[row] = f[row,:] . W_f2 + b_f2  -- FP32 STORE (d_out is float*)
__global__ __launch_bounds__(256) void f2_kernel(
    const ushort_t* __restrict__ fb, const float* __restrict__ w,
    const float* __restrict__ b2, float* __restrict__ out) {
  int wave = threadIdx.x >> 6, lane = threadIdx.x & 63;
  int row = blockIdx.x * 4 + wave;
  const ushort_t* fr = fb + (size_t)row * FFN_N;
  float s = 0.f;
#pragma unroll
  for (int i = 0; i < 16; i++) { int c = lane + i * 64; s += bf2f(fr[c]) * w[c]; }
#pragma unroll
  for (int off = 1; off < 64; off <<= 1) s += __shfl_xor(s, off, 64);
  if (lane == 0) out[row] = s + b2[0];
}

// ---------------------------------------------------------------------------
extern "C" void kernel_launch(void* const* d_in, const int* in_sizes, int n_in,
                              void* d_out, int out_size, void* d_ws, size_t ws_size,
                              hipStream_t stream) {
  const float* x     = (const float*)d_in[0];
  const int*   edge  = (const int*)d_in[1];
  const float* W_msg = (const float*)d_in[2];
  const float* b_msg = (const float*)d_in[3];
  const float* W_ih  = (const float*)d_in[4];
  const float* b_ih  = (const float*)d_in[5];
  const float* W_hh  = (const float*)d_in[6];
  const float* b_hh  = (const float*)d_in[7];
  const float* W_in  = (const float*)d_in[8];
  const float* b_in  = (const float*)d_in[9];
  const float* W_out = (const float*)d_in[10];
  const float* b_out = (const float*)d_in[11];
  const float* ln_g  = (const float*)d_in[12];
  const float* ln_b  = (const float*)d_in[13];
  const float* W_lin = (const float*)d_in[14];
  const float* b_lin = (const float*)d_in[15];
  const float* W_f1  = (const float*)d_in[16];
  const float* b_f1  = (const float*)d_in[17];
  const float* W_f2  = (const float*)d_in[18];
  const float* b_f2  = (const float*)d_in[19];

  char* ws = (char*)d_ws;
  const size_t MB = 1024 * 1024;
  // Workspace: [0,33) as before (liveness-packed), bf16 conversions [33,44).
  float*    agg = (float*)(ws + 1 * MB);           // [1,9)   zero..GI
  ushort_t* hb  = (ushort_t*)(ws + 1 * MB);        // [1,5)   gru..OUT (agg dead)
  ushort_t* gib = (ushort_t*)(ws + 9 * MB);        // [9,21)  bf16 [E][3H], GI..gru
  ushort_t* ghb = (ushort_t*)(ws + 21 * MB);       // [21,33) bf16 [E][3H], GH..gru
  ushort_t* Qb  = (ushort_t*)(ws + 5 * MB);        // [5,9)   QKV..attn
  ushort_t* Kb  = (ushort_t*)(ws + 9 * MB);        // [9,13)  (gib dead)
  ushort_t* Vt  = (ushort_t*)(ws + 13 * MB);       // [13,17)
  ushort_t* ob  = (ushort_t*)(ws + 17 * MB);       // [17,21) attn..OUT
  float*    y   = (float*)(ws + 21 * MB);          // [21,29) fp32, OUT..ln (ghb dead)
  ushort_t* ynb = (ushort_t*)(ws + 29 * MB);       // [29,31) ln..LIN
  ushort_t* gb  = (ushort_t*)(ws + 31 * MB);       // [31,33) LIN..F1
  ushort_t* fb  = (ushort_t*)(ws + 5 * MB);        // [5,13)  bf16 [E][FFN], F1..f2

  // bf16 conversions (contiguous, written by cvt_ws_kernel)
  ushort_t* xb   = (ushort_t*)(ws + 33 * MB);      // [33,37) x bf16 [E][H]
  ushort_t* wbf  = (ushort_t*)(ws + 37 * MB);      // [37,44) weights bf16
  ushort_t* Wmsg_b = wbf;                          // 262144 elems
  ushort_t* Wih_b  = wbf + 262144;                 // 786432
  ushort_t* Whh_b  = wbf + 1048576;                // 786432
  ushort_t* Win_b  = wbf + 1835008;                // 786432
  ushort_t* Wout_b = wbf + 2621440;                // 262144
  ushort_t* Wlin_b = wbf + 2883584;                // 262144
  ushort_t* Wf1_b  = wbf + 3145728;                // 524288

  cvt_ws_kernel<<<2816, 256, 0, stream>>>(
      x, W_msg, W_ih, W_hh, W_in, W_out, W_lin, W_f1, xb);

  zero_f32_kernel<<<2048, 256, 0, stream>>>((float4*)agg);

  gemm_bt<MODE_MSG, 0><<<dim3(32, 8), 256, 0, stream>>>(
      xb, Wmsg_b, b_msg, H_N, nullptr, nullptr, edge, agg, nullptr,
      nullptr, nullptr, nullptr);

  gemm_bt<MODE_GI, 1><<<dim3(32, 24), 256, 0, stream>>>(
      agg, Wih_b, b_ih, H_N, nullptr, gib, nullptr, nullptr, nullptr,
      nullptr, nullptr, nullptr);

  gemm_bt<MODE_GH, 0><<<dim3(32, 24), 256, 0, stream>>>(
      xb, Whh_b, b_hh, H_N, nullptr, ghb, nullptr, nullptr, nullptr,
      nullptr, nullptr, nullptr);

  gru_kernel<<<8192, 256, 0, stream>>>(gib, ghb, x, hb);

  gemm_bt<MODE_QKV, 0><<<dim3(32, 24), 256, 0, stream>>>(
      hb, Win_b, b_in, H_N, nullptr, nullptr, nullptr, nullptr, nullptr,
      Qb, Kb, Vt);

  attn_kernel<<<dim3(64, 4), 512, 0, stream>>>(Qb, Kb, Vt, ob);

  gemm_bt<MODE_OUT, 0><<<dim3(32, 8), 256, 0, stream>>>(
      ob, Wout_b, b_out, H_N, y, nullptr, nullptr, nullptr, hb,
      nullptr, nullptr, nullptr);

  ln_kernel<<<1024, 256, 0, stream>>>(y, ln_g, ln_b, ynb);

  gemm_bt<MODE_LIN, 0><<<dim3(32, 8), 256, 0, stream>>>(
      ynb, Wlin_b, b_lin, H_N, nullptr, gb, nullptr, nullptr, nullptr,
      nullptr, nullptr, nullptr);

  gemm_bt<MODE_F1, 0><<<dim3(32, 16), 256, 0, stream>>>(
      gb, Wf1_b, b_f1, H_N, nullptr, fb, nullptr, nullptr, nullptr,
      nullptr, nullptr, nullptr);

  f2_kernel<<<1024, 256, 0, stream>>>(fb, W_f2, b_f2, (float*)d_out);
}